// Round 4
// baseline (131.387 us; speedup 1.0000x reference)
//
#include <hip/hip_runtime.h>
#include <hip/hip_bf16.h>

#define NPOS   100
#define BATCH  1024
#define DIN    384
#define DOUT   384
#define XROW   (NPOS * DIN)      // 38400 floats, batch-dim stride of x and out
#define WSLICE (DIN * DOUT)

#define BM 128                   // batch rows per block
#define BN 384                   // FULL d_out per block -> x read exactly once
#define BK 32
#define NK (DIN / BK)            // 12 K-steps
#define PITCH 40                 // 80B rows: 16B-aligned b128, rows cover all 32 banks

typedef __attribute__((ext_vector_type(8))) short bf16x8;
typedef __attribute__((ext_vector_type(16))) float f32x16;

__device__ __forceinline__ unsigned short f2bf(float f) {
  __hip_bfloat16 h = __float2bfloat16(f);
  return __builtin_bit_cast(unsigned short, h);
}

__device__ __forceinline__ uint2 pack4(float a, float b, float c, float d) {
  uint2 r;
  r.x = (unsigned)f2bf(a) | ((unsigned)f2bf(b) << 16);
  r.y = (unsigned)f2bf(c) | ((unsigned)f2bf(d) << 16);
  return r;
}

// ds ops visible, vmcnt NOT drained (global prefetch survives the barrier)
__device__ __forceinline__ void barrier_nodrain() {
  asm volatile("s_waitcnt lgkmcnt(0)" ::: "memory");
  __builtin_amdgcn_s_barrier();
}

__global__ __launch_bounds__(512, 2) void nlinear_kernel(
    const float* __restrict__ x, const float* __restrict__ w,
    const float* __restrict__ bias, float* __restrict__ out)
{
  __shared__ short lA[2][BM * PITCH];    // [b-row][k] bf16
  __shared__ short lB[2][BN * PITCH];    // [o-row][k] bf16 (B^T)

  const int tid  = threadIdx.x;
  const int lane = tid & 63;
  const int wave = tid >> 6;             // 8 waves: 2m x 4n
  const int wm   = wave >> 2;
  const int wn   = wave & 3;
  const int l31  = lane & 31;
  const int kHi  = (lane >> 5) * 8;

  // XCD-aware bijective swizzle: 800 blocks = 8 * 100.
  // slice-major within an XCD -> the 8 mt-blocks of a slice co-resident.
  const int bid   = blockIdx.x;
  const int swz   = (bid & 7) * 100 + (bid >> 3);
  const int slice = swz >> 3;
  const int mt    = swz & 7;

  const float* xbase = x    + (size_t)mt * BM * XROW + (size_t)slice * DIN;
  const float* wbase = w    + (size_t)slice * WSLICE;
  const float* bbase = bias + (size_t)slice * DOUT;
  float*       obase = out  + (size_t)mt * BM * XROW + (size_t)slice * DOUT;

  // A staging: 2 float4/thread, rows a_row0 and a_row0+64 (coalesced 128B runs)
  const int a_c4   = tid & 7;
  const int a_row0 = tid >> 3;           // 0..63
  // B staging: 4k x 4o register-transpose patches, o-contiguous global loads
  const int kb1 = tid >> 6;              // 0..7  (wave-uniform)
  const int ob1 = tid & 63;              // cols 0..255
  const int kb2 = tid >> 5;              // 0..7 for tid<256
  const int ob2 = 64 + (tid & 31);       // cols 256..383
  const bool p2 = (tid < 256);           // waves 0-3 (wave-uniform)

  float ga[2][4];
  float gb1[4][4];
  float gb2[4][4];

  auto G2R = [&](int k0) {
#pragma unroll
    for (int i = 0; i < 2; ++i) {
      const float4 v = *reinterpret_cast<const float4*>(
          xbase + (size_t)(a_row0 + 64 * i) * XROW + k0 + a_c4 * 4);
      ga[i][0] = v.x; ga[i][1] = v.y; ga[i][2] = v.z; ga[i][3] = v.w;
    }
#pragma unroll
    for (int dk = 0; dk < 4; ++dk) {
      const float4 v = *reinterpret_cast<const float4*>(
          wbase + (size_t)(k0 + kb1 * 4 + dk) * DOUT + ob1 * 4);
      gb1[dk][0] = v.x; gb1[dk][1] = v.y; gb1[dk][2] = v.z; gb1[dk][3] = v.w;
    }
    if (p2) {
#pragma unroll
      for (int dk = 0; dk < 4; ++dk) {
        const float4 v = *reinterpret_cast<const float4*>(
            wbase + (size_t)(k0 + kb2 * 4 + dk) * DOUT + ob2 * 4);
        gb2[dk][0] = v.x; gb2[dk][1] = v.y; gb2[dk][2] = v.z; gb2[dk][3] = v.w;
      }
    }
  };

  auto R2L = [&](int buf) {
#pragma unroll
    for (int i = 0; i < 2; ++i) {
      *reinterpret_cast<uint2*>(
          &lA[buf][(a_row0 + 64 * i) * PITCH + a_c4 * 4]) =
          pack4(ga[i][0], ga[i][1], ga[i][2], ga[i][3]);
    }
#pragma unroll
    for (int j = 0; j < 4; ++j) {   // B^T rows o, 4 k-shorts each (8B)
      *reinterpret_cast<uint2*>(
          &lB[buf][(ob1 * 4 + j) * PITCH + kb1 * 4]) =
          pack4(gb1[0][j], gb1[1][j], gb1[2][j], gb1[3][j]);
    }
    if (p2) {
#pragma unroll
      for (int j = 0; j < 4; ++j) {
        *reinterpret_cast<uint2*>(
            &lB[buf][(ob2 * 4 + j) * PITCH + kb2 * 4]) =
            pack4(gb2[0][j], gb2[1][j], gb2[2][j], gb2[3][j]);
      }
    }
  };

  f32x16 acc[2][3];
#pragma unroll
  for (int m = 0; m < 2; ++m)
#pragma unroll
    for (int n = 0; n < 3; ++n)
#pragma unroll
      for (int r = 0; r < 16; ++r)
        acc[m][n][r] = 0.f;

  G2R(0);
  R2L(0);
  barrier_nodrain();
  G2R(BK);

  auto STEP = [&](int ks, int cb) {
    if (ks + 1 < NK) R2L(cb ^ 1);
    if (ks + 2 < NK) G2R((ks + 2) * BK);
    bf16x8 af[2][2];   // [kk][m]
    bf16x8 bf[2][3];   // [kk][n]
#pragma unroll
    for (int kk = 0; kk < 2; ++kk)
#pragma unroll
      for (int m = 0; m < 2; ++m)
        af[kk][m] = *reinterpret_cast<const bf16x8*>(
            &lA[cb][(wm * 64 + m * 32 + l31) * PITCH + kk * 16 + kHi]);
#pragma unroll
    for (int kk = 0; kk < 2; ++kk)
#pragma unroll
      for (int n = 0; n < 3; ++n)
        bf[kk][n] = *reinterpret_cast<const bf16x8*>(
            &lB[cb][(wn * 96 + n * 32 + l31) * PITCH + kk * 16 + kHi]);
#pragma unroll
    for (int kk = 0; kk < 2; ++kk)
#pragma unroll
      for (int m = 0; m < 2; ++m)
#pragma unroll
        for (int n = 0; n < 3; ++n)
          acc[m][n] = __builtin_amdgcn_mfma_f32_32x32x16_bf16(
              af[kk][m], bf[kk][n], acc[m][n], 0, 0, 0);
    barrier_nodrain();
  };

#pragma unroll
  for (int ks = 0; ks < NK; ks += 2) {
    STEP(ks, 0);
    STEP(ks + 1, 1);
  }

  // Epilogue. 32x32 D frag: col = lane&31, row = (r&3) + 8*(r>>2) + 4*(lane>>5)
  float bv[3];
#pragma unroll
  for (int n = 0; n < 3; ++n) bv[n] = bbase[wn * 96 + n * 32 + l31];

  const int rbase = wm * 64 + ((lane >> 5) << 2);
#pragma unroll
  for (int m = 0; m < 2; ++m) {
#pragma unroll
    for (int n = 0; n < 3; ++n) {
      const int c = wn * 96 + n * 32 + l31;
#pragma unroll
      for (int r = 0; r < 16; ++r) {
        const int row = rbase + m * 32 + (r & 3) + 8 * (r >> 2);
        obase[(size_t)row * XROW + c] = acc[m][n][r] + bv[n];
      }
    }
  }
}

extern "C" void kernel_launch(void* const* d_in, const int* in_sizes, int n_in,
                              void* d_out, int out_size, void* d_ws, size_t ws_size,
                              hipStream_t stream) {
  const float* x  = (const float*)d_in[0];
  const float* w  = (const float*)d_in[1];
  const float* b  = (const float*)d_in[2];
  float* out      = (float*)d_out;
  const int grid  = NPOS * (BATCH / BM);  // 800
  nlinear_kernel<<<grid, 512, 0, stream>>>(x, w, b, out);
}